// Round 5
// baseline (290.489 us; speedup 1.0000x reference)
//
#include <hip/hip_runtime.h>

#define LOG2F 0.69314718055994530942f
#define CAP 64   // per-node bucket capacity; deg ~ Poisson(16), overflow path below

__device__ __forceinline__ float4 f4add(float4 a, float4 b) {
    return make_float4(a.x + b.x, a.y + b.y, a.z + b.z, a.w + b.w);
}

// ---------------------------------------------------------------------------
// Kernel 0: zero counts/ovf_cnt + detect int64 vs int32 edge_index layout.
// ---------------------------------------------------------------------------
__global__ __launch_bounds__(256) void zero_detect_kernel(
        const unsigned int* __restrict__ words,
        int* __restrict__ counts, int* __restrict__ ovf_cnt,
        int* __restrict__ flag, int N) {
    const int gid = blockIdx.x * blockDim.x + threadIdx.x;
    if (gid < N) counts[gid] = 0;
    if (gid == 0) *ovf_cnt = 0;
    if (blockIdx.x == 0 && threadIdx.x < 64) {
        const int lane = threadIdx.x;
        unsigned int acc = 0;
        #pragma unroll
        for (int r = 0; r < 4; ++r) acc |= words[1 + 2 * (lane + 64 * r)];
        int any_nonzero = __any(acc != 0u);
        if (lane == 0) *flag = any_nonzero ? 0 : 1;
    }
}

__device__ __forceinline__ int load_target(const void* idx, const int* flag,
                                           int E, int e) {
    if (*flag) return (int)((const long long*)idx)[E + e];
    return ((const int*)idx)[E + e];
}

// ---------------------------------------------------------------------------
// Kernel 1: direct bucketing (fused hist+fill, no scan).
// ---------------------------------------------------------------------------
__global__ __launch_bounds__(256) void bucket_kernel(
        const void* __restrict__ idx, const int* __restrict__ flag,
        int* __restrict__ counts, int* __restrict__ elist64,
        int* __restrict__ ovf_cnt, int* __restrict__ ovf_n,
        int* __restrict__ ovf_e, int E) {
    int e = blockIdx.x * blockDim.x + threadIdx.x;
    if (e >= E) return;
    int n = load_target(idx, flag, E, e);
    int pos = atomicAdd(&counts[n], 1);
    if (pos < CAP) {
        elist64[(n << 6) + pos] = e;
    } else {
        int op = atomicAdd(ovf_cnt, 1);
        ovf_n[op] = n;
        ovf_e[op] = e;
    }
}

// ---------------------------------------------------------------------------
// Kernel 2: gather-reduce, wave-per-node. 256 threads = 4 waves = 4 nodes.
// Each wave: edge ids live in lane registers (one coalesced load), broadcast
// via __shfl; per edge two 1KB wave-loads; unroll x4 -> 8 loads in flight.
// No LDS, no barriers. s computed via shfl_xor(32).
// ---------------------------------------------------------------------------
__global__ __launch_bounds__(256) void gather_kernel(
        const float4* __restrict__ edge_feats4,
        const int* __restrict__ elist64,
        const int* __restrict__ counts,
        const int* __restrict__ ovf_cnt,
        const int* __restrict__ ovf_n,
        const int* __restrict__ ovf_e,
        const float* __restrict__ node_vec,
        float* __restrict__ out1,
        float* __restrict__ s,
        int N) {
    const int wave = threadIdx.x >> 6;
    const int lane = threadIdx.x & 63;
    const int n = blockIdx.x * 4 + wave;
    if (n >= N) return;

    const int cnt = counts[n];
    const int c = min(cnt, CAP);

    int el = 0;
    if (lane < c) el = elist64[(n << 6) + lane];

    float4 a0 = make_float4(0.f, 0.f, 0.f, 0.f);   // float4 cols [lane]      (bytes 0..1023)
    float4 a1 = make_float4(0.f, 0.f, 0.f, 0.f);   // float4 cols [64+lane]   (bytes 1024..2047)

    int it = 0;
    for (; it + 4 <= c; it += 4) {
        const long long e0 = __shfl(el, it + 0);
        const long long e1 = __shfl(el, it + 1);
        const long long e2 = __shfl(el, it + 2);
        const long long e3 = __shfl(el, it + 3);
        float4 v00 = edge_feats4[e0 * 128 + lane];
        float4 v01 = edge_feats4[e0 * 128 + 64 + lane];
        float4 v10 = edge_feats4[e1 * 128 + lane];
        float4 v11 = edge_feats4[e1 * 128 + 64 + lane];
        float4 v20 = edge_feats4[e2 * 128 + lane];
        float4 v21 = edge_feats4[e2 * 128 + 64 + lane];
        float4 v30 = edge_feats4[e3 * 128 + lane];
        float4 v31 = edge_feats4[e3 * 128 + 64 + lane];
        a0 = f4add(a0, f4add(f4add(v00, v10), f4add(v20, v30)));
        a1 = f4add(a1, f4add(f4add(v01, v11), f4add(v21, v31)));
    }
    for (; it < c; ++it) {
        const long long e = __shfl(el, it);
        a0 = f4add(a0, edge_feats4[e * 128 + lane]);
        a1 = f4add(a1, edge_feats4[e * 128 + 64 + lane]);
    }
    if (cnt > CAP) {   // rare overflow path (correctness only)
        const int oc = *ovf_cnt;
        for (int i = 0; i < oc; ++i) {
            if (ovf_n[i] == n) {
                const long long e = ovf_e[i];
                a0 = f4add(a0, edge_feats4[e * 128 + lane]);
                a1 = f4add(a1, edge_feats4[e * 128 + 64 + lane]);
            }
        }
    }

    // out1 = node_vec + agg[:,1:,:]  (float4 cols 32..127 of agg)
    const float4* nv = (const float4*)node_vec + (long long)n * 96;
    float4*       o1 = (float4*)out1 + (long long)n * 96;
    if (lane >= 32) {
        o1[lane - 32] = f4add(nv[lane - 32], a0);   // agg cols 32..63
    }
    o1[32 + lane] = f4add(nv[32 + lane], a1);       // agg cols 64..127

    // s = sum over k: t[lane] = agg[lane] + agg[64+lane]; fold lane^32.
    float4 t = f4add(a0, a1);
    float4 u;
    u.x = __shfl_xor(t.x, 32);
    u.y = __shfl_xor(t.y, 32);
    u.z = __shfl_xor(t.z, 32);
    u.w = __shfl_xor(t.w, 32);
    if (lane < 32) {
        ((float4*)s)[(long long)n * 32 + lane] = f4add(t, u);
    }
}

// ---------------------------------------------------------------------------
// Kernel 3: per-node MLP. Block = 256 threads, 16 nodes/block.
// ---------------------------------------------------------------------------
__global__ __launch_bounds__(256) void node_kernel(
        const float* __restrict__ s,
        const float* __restrict__ node_sca,
        const float* __restrict__ W1, const float* __restrict__ b1,
        const float* __restrict__ W2, const float* __restrict__ b2,
        float* __restrict__ out0,
        int N) {
    __shared__ float s_lds[16][128];
    __shared__ float h_lds[16][128];

    const int tid = threadIdx.x;
    const int nbase = blockIdx.x * 16;

    {
        const float4* sg = (const float4*)s;
        #pragma unroll
        for (int step = 0; step < 2; ++step) {
            int idx = tid + step * 256;
            int m = idx >> 5;
            int q = idx & 31;
            int n = nbase + m;
            float4 v = make_float4(0.f, 0.f, 0.f, 0.f);
            if (n < N) v = sg[(long long)n * 32 + q];
            *(float4*)&s_lds[m][q * 4] = v;
        }
    }
    __syncthreads();

    const int j = tid & 127;
    const int mbase = (tid >> 7) * 8;

    {
        float acc[8] = {0.f, 0.f, 0.f, 0.f, 0.f, 0.f, 0.f, 0.f};
        #pragma unroll 4
        for (int f0 = 0; f0 < 128; f0 += 4) {
            const float w0 = W1[(f0 + 0) * 128 + j];
            const float w1 = W1[(f0 + 1) * 128 + j];
            const float w2 = W1[(f0 + 2) * 128 + j];
            const float w3 = W1[(f0 + 3) * 128 + j];
            #pragma unroll
            for (int m = 0; m < 8; ++m) {
                float4 sv = *(const float4*)&s_lds[mbase + m][f0];
                acc[m] = fmaf(sv.x, w0, acc[m]);
                acc[m] = fmaf(sv.y, w1, acc[m]);
                acc[m] = fmaf(sv.z, w2, acc[m]);
                acc[m] = fmaf(sv.w, w3, acc[m]);
            }
        }
        const float bj = b1[j];
        #pragma unroll
        for (int m = 0; m < 8; ++m) {
            float x = acc[m] + bj;
            float h = fmaxf(x, 0.f) + log1pf(expf(-fabsf(x))) - LOG2F;
            h_lds[mbase + m][j] = h;
        }
    }
    __syncthreads();

    {
        float acc[8] = {0.f, 0.f, 0.f, 0.f, 0.f, 0.f, 0.f, 0.f};
        #pragma unroll 4
        for (int f0 = 0; f0 < 128; f0 += 4) {
            const float w0 = W2[(f0 + 0) * 128 + j];
            const float w1 = W2[(f0 + 1) * 128 + j];
            const float w2 = W2[(f0 + 2) * 128 + j];
            const float w3 = W2[(f0 + 3) * 128 + j];
            #pragma unroll
            for (int m = 0; m < 8; ++m) {
                float4 hv = *(const float4*)&h_lds[mbase + m][f0];
                acc[m] = fmaf(hv.x, w0, acc[m]);
                acc[m] = fmaf(hv.y, w1, acc[m]);
                acc[m] = fmaf(hv.z, w2, acc[m]);
                acc[m] = fmaf(hv.w, w3, acc[m]);
            }
        }
        const float bj = b2[j];
        #pragma unroll
        for (int m = 0; m < 8; ++m) {
            const int n = nbase + mbase + m;
            if (n < N) {
                out0[(long long)n * 128 + j] =
                    node_sca[(long long)n * 128 + j] + acc[m] + bj;
            }
        }
    }
}

extern "C" void kernel_launch(void* const* d_in, const int* in_sizes, int n_in,
                              void* d_out, int out_size, void* d_ws, size_t ws_size,
                              hipStream_t stream) {
    const float* node_sca   = (const float*)d_in[0];
    const float* node_vec   = (const float*)d_in[1];
    const float* edge_feats = (const float*)d_in[2];
    const void*  edge_index = d_in[3];
    const float* W1 = (const float*)d_in[4];
    const float* b1 = (const float*)d_in[5];
    const float* W2 = (const float*)d_in[6];
    const float* b2 = (const float*)d_in[7];

    const int H = in_sizes[5];            // 128
    const int N = in_sizes[0] / H;        // 25000
    const int E = in_sizes[3] / 2;        // 400000

    char* w = (char*)d_ws;
    auto take = [&](size_t bytes) {
        char* p = w;
        w += (bytes + 15) & ~(size_t)15;
        return p;
    };
    int*   counts  = (int*)take(sizeof(int) * (size_t)N);
    int*   elist64 = (int*)take(sizeof(int) * (size_t)N * CAP);
    int*   ovf_cnt = (int*)take(sizeof(int));
    int*   ovf_n   = (int*)take(sizeof(int) * (size_t)E);
    int*   ovf_e   = (int*)take(sizeof(int) * (size_t)E);
    float* s       = (float*)take(sizeof(float) * (size_t)N * 128);
    int*   flag    = (int*)take(sizeof(int));

    float* out0 = (float*)d_out;               // (N, 128)
    float* out1 = out0 + (long long)N * 128;   // (N, 3, 128)

    zero_detect_kernel<<<(N + 255) / 256, 256, 0, stream>>>(
        (const unsigned int*)edge_index, counts, ovf_cnt, flag, N);

    bucket_kernel<<<(E + 255) / 256, 256, 0, stream>>>(
        edge_index, flag, counts, elist64, ovf_cnt, ovf_n, ovf_e, E);

    gather_kernel<<<(N + 3) / 4, 256, 0, stream>>>(
        (const float4*)edge_feats, elist64, counts, ovf_cnt, ovf_n, ovf_e,
        node_vec, out1, s, N);

    node_kernel<<<(N + 15) / 16, 256, 0, stream>>>(
        s, node_sca, W1, b1, W2, b2, out0, N);
}

// Round 6
// 261.046 us; speedup vs baseline: 1.1128x; 1.1128x over previous
//
#include <hip/hip_runtime.h>

#define LOG2F 0.69314718055994530942f
#define CAP 64   // per-node bucket capacity; deg ~ Poisson(16), overflow path below

typedef float f32x4 __attribute__((ext_vector_type(4)));

__device__ __forceinline__ float4 f4add(float4 a, float4 b) {
    return make_float4(a.x + b.x, a.y + b.y, a.z + b.z, a.w + b.w);
}

// non-temporal 16B load/store (single-use streaming data: skip cache fill)
__device__ __forceinline__ float4 nt_load4(const float4* p) {
    f32x4 v = __builtin_nontemporal_load((const f32x4*)p);
    return make_float4(v.x, v.y, v.z, v.w);
}
__device__ __forceinline__ void nt_store4(float4* p, float4 v) {
    f32x4 t = {v.x, v.y, v.z, v.w};
    __builtin_nontemporal_store(t, (f32x4*)p);
}

// ---------------------------------------------------------------------------
// Kernel 0: zero counts/ovf_cnt + detect int64 vs int32 edge_index layout.
// ---------------------------------------------------------------------------
__global__ __launch_bounds__(256) void zero_detect_kernel(
        const unsigned int* __restrict__ words,
        int* __restrict__ counts, int* __restrict__ ovf_cnt,
        int* __restrict__ flag, int N) {
    const int gid = blockIdx.x * blockDim.x + threadIdx.x;
    if (gid < N) counts[gid] = 0;
    if (gid == 0) *ovf_cnt = 0;
    if (blockIdx.x == 0 && threadIdx.x < 64) {
        const int lane = threadIdx.x;
        unsigned int acc = 0;
        #pragma unroll
        for (int r = 0; r < 4; ++r) acc |= words[1 + 2 * (lane + 64 * r)];
        int any_nonzero = __any(acc != 0u);
        if (lane == 0) *flag = any_nonzero ? 0 : 1;
    }
}

__device__ __forceinline__ int load_target(const void* idx, const int* flag,
                                           int E, int e) {
    if (*flag) return (int)((const long long*)idx)[E + e];
    return ((const int*)idx)[E + e];
}

// ---------------------------------------------------------------------------
// Kernel 1: direct bucketing (fused hist+fill, no scan).
// ---------------------------------------------------------------------------
__global__ __launch_bounds__(256) void bucket_kernel(
        const void* __restrict__ idx, const int* __restrict__ flag,
        int* __restrict__ counts, int* __restrict__ elist64,
        int* __restrict__ ovf_cnt, int* __restrict__ ovf_n,
        int* __restrict__ ovf_e, int E) {
    int e = blockIdx.x * blockDim.x + threadIdx.x;
    if (e >= E) return;
    int n = load_target(idx, flag, E, e);
    int pos = atomicAdd(&counts[n], 1);
    if (pos < CAP) {
        elist64[(n << 6) + pos] = e;
    } else {
        int op = atomicAdd(ovf_cnt, 1);
        ovf_n[op] = n;
        ovf_e[op] = e;
    }
}

// ---------------------------------------------------------------------------
// Kernel 2: gather-reduce, wave-per-node. 256 threads = 4 waves = 4 nodes.
// Edge ids in lane registers, broadcast via __shfl; per edge two 1KB
// wave-loads (non-temporal); unroll x4 -> 8 loads in flight. No barriers.
// ---------------------------------------------------------------------------
__global__ __launch_bounds__(256) void gather_kernel(
        const float4* __restrict__ edge_feats4,
        const int* __restrict__ elist64,
        const int* __restrict__ counts,
        const int* __restrict__ ovf_cnt,
        const int* __restrict__ ovf_n,
        const int* __restrict__ ovf_e,
        const float* __restrict__ node_vec,
        float* __restrict__ out1,
        float* __restrict__ s,
        int N) {
    const int wave = threadIdx.x >> 6;
    const int lane = threadIdx.x & 63;
    const int n = blockIdx.x * 4 + wave;
    if (n >= N) return;

    const int cnt = counts[n];
    const int c = min(cnt, CAP);

    int el = 0;
    if (lane < c) el = elist64[(n << 6) + lane];

    float4 a0 = make_float4(0.f, 0.f, 0.f, 0.f);   // float4 cols [lane]
    float4 a1 = make_float4(0.f, 0.f, 0.f, 0.f);   // float4 cols [64+lane]

    int it = 0;
    for (; it + 4 <= c; it += 4) {
        const long long e0 = __shfl(el, it + 0);
        const long long e1 = __shfl(el, it + 1);
        const long long e2 = __shfl(el, it + 2);
        const long long e3 = __shfl(el, it + 3);
        float4 v00 = nt_load4(&edge_feats4[e0 * 128 + lane]);
        float4 v01 = nt_load4(&edge_feats4[e0 * 128 + 64 + lane]);
        float4 v10 = nt_load4(&edge_feats4[e1 * 128 + lane]);
        float4 v11 = nt_load4(&edge_feats4[e1 * 128 + 64 + lane]);
        float4 v20 = nt_load4(&edge_feats4[e2 * 128 + lane]);
        float4 v21 = nt_load4(&edge_feats4[e2 * 128 + 64 + lane]);
        float4 v30 = nt_load4(&edge_feats4[e3 * 128 + lane]);
        float4 v31 = nt_load4(&edge_feats4[e3 * 128 + 64 + lane]);
        a0 = f4add(a0, f4add(f4add(v00, v10), f4add(v20, v30)));
        a1 = f4add(a1, f4add(f4add(v01, v11), f4add(v21, v31)));
    }
    for (; it < c; ++it) {
        const long long e = __shfl(el, it);
        a0 = f4add(a0, nt_load4(&edge_feats4[e * 128 + lane]));
        a1 = f4add(a1, nt_load4(&edge_feats4[e * 128 + 64 + lane]));
    }
    if (cnt > CAP) {   // rare overflow path (correctness only)
        const int oc = *ovf_cnt;
        for (int i = 0; i < oc; ++i) {
            if (ovf_n[i] == n) {
                const long long e = ovf_e[i];
                a0 = f4add(a0, nt_load4(&edge_feats4[e * 128 + lane]));
                a1 = f4add(a1, nt_load4(&edge_feats4[e * 128 + 64 + lane]));
            }
        }
    }

    // out1 = node_vec + agg[:,1:,:]  (float4 cols 32..127 of agg); NT stores.
    const float4* nv = (const float4*)node_vec + (long long)n * 96;
    float4*       o1 = (float4*)out1 + (long long)n * 96;
    if (lane >= 32) {
        nt_store4(&o1[lane - 32], f4add(nt_load4(&nv[lane - 32]), a0));
    }
    nt_store4(&o1[32 + lane], f4add(nt_load4(&nv[32 + lane]), a1));

    // s = sum over k (normal store: node_kernel re-reads it -> want L2 hit)
    float4 t = f4add(a0, a1);
    float4 u;
    u.x = __shfl_xor(t.x, 32);
    u.y = __shfl_xor(t.y, 32);
    u.z = __shfl_xor(t.z, 32);
    u.w = __shfl_xor(t.w, 32);
    if (lane < 32) {
        ((float4*)s)[(long long)n * 32 + lane] = f4add(t, u);
    }
}

// ---------------------------------------------------------------------------
// Kernel 3: per-node MLP. Block = 256 threads, 16 nodes/block.
// ---------------------------------------------------------------------------
__global__ __launch_bounds__(256) void node_kernel(
        const float* __restrict__ s,
        const float* __restrict__ node_sca,
        const float* __restrict__ W1, const float* __restrict__ b1,
        const float* __restrict__ W2, const float* __restrict__ b2,
        float* __restrict__ out0,
        int N) {
    __shared__ float s_lds[16][128];
    __shared__ float h_lds[16][128];

    const int tid = threadIdx.x;
    const int nbase = blockIdx.x * 16;

    {
        const float4* sg = (const float4*)s;
        #pragma unroll
        for (int step = 0; step < 2; ++step) {
            int idx = tid + step * 256;
            int m = idx >> 5;
            int q = idx & 31;
            int n = nbase + m;
            float4 v = make_float4(0.f, 0.f, 0.f, 0.f);
            if (n < N) v = sg[(long long)n * 32 + q];
            *(float4*)&s_lds[m][q * 4] = v;
        }
    }
    __syncthreads();

    const int j = tid & 127;
    const int mbase = (tid >> 7) * 8;

    {
        float acc[8] = {0.f, 0.f, 0.f, 0.f, 0.f, 0.f, 0.f, 0.f};
        #pragma unroll 4
        for (int f0 = 0; f0 < 128; f0 += 4) {
            const float w0 = W1[(f0 + 0) * 128 + j];
            const float w1 = W1[(f0 + 1) * 128 + j];
            const float w2 = W1[(f0 + 2) * 128 + j];
            const float w3 = W1[(f0 + 3) * 128 + j];
            #pragma unroll
            for (int m = 0; m < 8; ++m) {
                float4 sv = *(const float4*)&s_lds[mbase + m][f0];
                acc[m] = fmaf(sv.x, w0, acc[m]);
                acc[m] = fmaf(sv.y, w1, acc[m]);
                acc[m] = fmaf(sv.z, w2, acc[m]);
                acc[m] = fmaf(sv.w, w3, acc[m]);
            }
        }
        const float bj = b1[j];
        #pragma unroll
        for (int m = 0; m < 8; ++m) {
            float x = acc[m] + bj;
            float h = fmaxf(x, 0.f) + log1pf(expf(-fabsf(x))) - LOG2F;
            h_lds[mbase + m][j] = h;
        }
    }
    __syncthreads();

    {
        float acc[8] = {0.f, 0.f, 0.f, 0.f, 0.f, 0.f, 0.f, 0.f};
        #pragma unroll 4
        for (int f0 = 0; f0 < 128; f0 += 4) {
            const float w0 = W2[(f0 + 0) * 128 + j];
            const float w1 = W2[(f0 + 1) * 128 + j];
            const float w2 = W2[(f0 + 2) * 128 + j];
            const float w3 = W2[(f0 + 3) * 128 + j];
            #pragma unroll
            for (int m = 0; m < 8; ++m) {
                float4 hv = *(const float4*)&h_lds[mbase + m][f0];
                acc[m] = fmaf(hv.x, w0, acc[m]);
                acc[m] = fmaf(hv.y, w1, acc[m]);
                acc[m] = fmaf(hv.z, w2, acc[m]);
                acc[m] = fmaf(hv.w, w3, acc[m]);
            }
        }
        const float bj = b2[j];
        #pragma unroll
        for (int m = 0; m < 8; ++m) {
            const int n = nbase + mbase + m;
            if (n < N) {
                float4 dummy;
                float v = node_sca[(long long)n * 128 + j] + acc[m] + bj;
                __builtin_nontemporal_store(v, &out0[(long long)n * 128 + j]);
                (void)dummy;
            }
        }
    }
}

extern "C" void kernel_launch(void* const* d_in, const int* in_sizes, int n_in,
                              void* d_out, int out_size, void* d_ws, size_t ws_size,
                              hipStream_t stream) {
    const float* node_sca   = (const float*)d_in[0];
    const float* node_vec   = (const float*)d_in[1];
    const float* edge_feats = (const float*)d_in[2];
    const void*  edge_index = d_in[3];
    const float* W1 = (const float*)d_in[4];
    const float* b1 = (const float*)d_in[5];
    const float* W2 = (const float*)d_in[6];
    const float* b2 = (const float*)d_in[7];

    const int H = in_sizes[5];            // 128
    const int N = in_sizes[0] / H;        // 25000
    const int E = in_sizes[3] / 2;        // 400000

    char* w = (char*)d_ws;
    auto take = [&](size_t bytes) {
        char* p = w;
        w += (bytes + 15) & ~(size_t)15;
        return p;
    };
    int*   counts  = (int*)take(sizeof(int) * (size_t)N);
    int*   elist64 = (int*)take(sizeof(int) * (size_t)N * CAP);
    int*   ovf_cnt = (int*)take(sizeof(int));
    int*   ovf_n   = (int*)take(sizeof(int) * (size_t)E);
    int*   ovf_e   = (int*)take(sizeof(int) * (size_t)E);
    float* s       = (float*)take(sizeof(float) * (size_t)N * 128);
    int*   flag    = (int*)take(sizeof(int));

    float* out0 = (float*)d_out;               // (N, 128)
    float* out1 = out0 + (long long)N * 128;   // (N, 3, 128)

    zero_detect_kernel<<<(N + 255) / 256, 256, 0, stream>>>(
        (const unsigned int*)edge_index, counts, ovf_cnt, flag, N);

    bucket_kernel<<<(E + 255) / 256, 256, 0, stream>>>(
        edge_index, flag, counts, elist64, ovf_cnt, ovf_n, ovf_e, E);

    gather_kernel<<<(N + 3) / 4, 256, 0, stream>>>(
        (const float4*)edge_feats, elist64, counts, ovf_cnt, ovf_n, ovf_e,
        node_vec, out1, s, N);

    node_kernel<<<(N + 15) / 16, 256, 0, stream>>>(
        s, node_sca, W1, b1, W2, b2, out0, N);
}

// Round 7
// 260.850 us; speedup vs baseline: 1.1136x; 1.0008x over previous
//
#include <hip/hip_runtime.h>

#define LOG2F 0.69314718055994530942f
#define CAP 64   // per-node bucket capacity; deg ~ Poisson(16), overflow path below

typedef float f32x4 __attribute__((ext_vector_type(4)));

__device__ __forceinline__ float4 f4add(float4 a, float4 b) {
    return make_float4(a.x + b.x, a.y + b.y, a.z + b.z, a.w + b.w);
}

// non-temporal 16B load/store (single-use streaming data: skip cache fill)
__device__ __forceinline__ float4 nt_load4(const float4* p) {
    f32x4 v = __builtin_nontemporal_load((const f32x4*)p);
    return make_float4(v.x, v.y, v.z, v.w);
}
__device__ __forceinline__ void nt_store4(float4* p, float4 v) {
    f32x4 t = {v.x, v.y, v.z, v.w};
    __builtin_nontemporal_store(t, (f32x4*)p);
}

// ---------------------------------------------------------------------------
// Kernel 0: zero counts/ovf_cnt + detect int64 vs int32 edge_index layout.
// ---------------------------------------------------------------------------
__global__ __launch_bounds__(256) void zero_detect_kernel(
        const unsigned int* __restrict__ words,
        int* __restrict__ counts, int* __restrict__ ovf_cnt,
        int* __restrict__ flag, int N) {
    const int gid = blockIdx.x * blockDim.x + threadIdx.x;
    if (gid < N) counts[gid] = 0;
    if (gid == 0) *ovf_cnt = 0;
    if (blockIdx.x == 0 && threadIdx.x < 64) {
        const int lane = threadIdx.x;
        unsigned int acc = 0;
        #pragma unroll
        for (int r = 0; r < 4; ++r) acc |= words[1 + 2 * (lane + 64 * r)];
        int any_nonzero = __any(acc != 0u);
        if (lane == 0) *flag = any_nonzero ? 0 : 1;
    }
}

__device__ __forceinline__ int load_target(const void* idx, const int* flag,
                                           int E, int e) {
    if (*flag) return (int)((const long long*)idx)[E + e];
    return ((const int*)idx)[E + e];
}

// ---------------------------------------------------------------------------
// Kernel 1: direct bucketing (fused hist+fill, no scan).
// ---------------------------------------------------------------------------
__global__ __launch_bounds__(256) void bucket_kernel(
        const void* __restrict__ idx, const int* __restrict__ flag,
        int* __restrict__ counts, int* __restrict__ elist64,
        int* __restrict__ ovf_cnt, int* __restrict__ ovf_n,
        int* __restrict__ ovf_e, int E) {
    int e = blockIdx.x * blockDim.x + threadIdx.x;
    if (e >= E) return;
    int n = load_target(idx, flag, E, e);
    int pos = atomicAdd(&counts[n], 1);
    if (pos < CAP) {
        elist64[(n << 6) + pos] = e;
    } else {
        int op = atomicAdd(ovf_cnt, 1);
        ovf_n[op] = n;
        ovf_e[op] = e;
    }
}

// ---------------------------------------------------------------------------
// Kernel 2: gather-reduce, wave-per-node. 256 threads = 4 waves = 4 nodes.
// Edge ids in lane registers (one NT coalesced load), broadcast via __shfl;
// per edge two 1KB wave-loads (NT); unroll x4 -> 8 loads in flight.
// node_vec preloaded BEFORE the edge loop so its latency hides under edge
// streaming. No LDS for data, no barriers.
// ---------------------------------------------------------------------------
__global__ __launch_bounds__(256) void gather_kernel(
        const float4* __restrict__ edge_feats4,
        const int* __restrict__ elist64,
        const int* __restrict__ counts,
        const int* __restrict__ ovf_cnt,
        const int* __restrict__ ovf_n,
        const int* __restrict__ ovf_e,
        const float* __restrict__ node_vec,
        float* __restrict__ out1,
        float* __restrict__ s,
        int N) {
    const int wave = threadIdx.x >> 6;
    const int lane = threadIdx.x & 63;
    const int n = blockIdx.x * 4 + wave;
    if (n >= N) return;

    const int cnt = counts[n];
    const int c = min(cnt, CAP);

    int el = 0;
    if (lane < c) el = __builtin_nontemporal_load(&elist64[(n << 6) + lane]);

    // Preload node_vec rows (single-use, NT) so they complete under the loop.
    const float4* nv = (const float4*)node_vec + (long long)n * 96;
    float4 nv0 = make_float4(0.f, 0.f, 0.f, 0.f);
    if (lane >= 32) nv0 = nt_load4(&nv[lane - 32]);
    float4 nv1 = nt_load4(&nv[32 + lane]);

    float4 a0 = make_float4(0.f, 0.f, 0.f, 0.f);   // float4 cols [lane]
    float4 a1 = make_float4(0.f, 0.f, 0.f, 0.f);   // float4 cols [64+lane]

    int it = 0;
    for (; it + 4 <= c; it += 4) {
        const long long e0 = __shfl(el, it + 0);
        const long long e1 = __shfl(el, it + 1);
        const long long e2 = __shfl(el, it + 2);
        const long long e3 = __shfl(el, it + 3);
        float4 v00 = nt_load4(&edge_feats4[e0 * 128 + lane]);
        float4 v01 = nt_load4(&edge_feats4[e0 * 128 + 64 + lane]);
        float4 v10 = nt_load4(&edge_feats4[e1 * 128 + lane]);
        float4 v11 = nt_load4(&edge_feats4[e1 * 128 + 64 + lane]);
        float4 v20 = nt_load4(&edge_feats4[e2 * 128 + lane]);
        float4 v21 = nt_load4(&edge_feats4[e2 * 128 + 64 + lane]);
        float4 v30 = nt_load4(&edge_feats4[e3 * 128 + lane]);
        float4 v31 = nt_load4(&edge_feats4[e3 * 128 + 64 + lane]);
        a0 = f4add(a0, f4add(f4add(v00, v10), f4add(v20, v30)));
        a1 = f4add(a1, f4add(f4add(v01, v11), f4add(v21, v31)));
    }
    for (; it < c; ++it) {
        const long long e = __shfl(el, it);
        a0 = f4add(a0, nt_load4(&edge_feats4[e * 128 + lane]));
        a1 = f4add(a1, nt_load4(&edge_feats4[e * 128 + 64 + lane]));
    }
    if (cnt > CAP) {   // rare overflow path (correctness only)
        const int oc = *ovf_cnt;
        for (int i = 0; i < oc; ++i) {
            if (ovf_n[i] == n) {
                const long long e = ovf_e[i];
                a0 = f4add(a0, nt_load4(&edge_feats4[e * 128 + lane]));
                a1 = f4add(a1, nt_load4(&edge_feats4[e * 128 + 64 + lane]));
            }
        }
    }

    // out1 = node_vec + agg[:,1:,:]  (float4 cols 32..127 of agg); NT stores.
    float4* o1 = (float4*)out1 + (long long)n * 96;
    if (lane >= 32) {
        nt_store4(&o1[lane - 32], f4add(nv0, a0));
    }
    nt_store4(&o1[32 + lane], f4add(nv1, a1));

    // s = sum over k (normal store: node_kernel re-reads it -> want L2 hit)
    float4 t = f4add(a0, a1);
    float4 u;
    u.x = __shfl_xor(t.x, 32);
    u.y = __shfl_xor(t.y, 32);
    u.z = __shfl_xor(t.z, 32);
    u.w = __shfl_xor(t.w, 32);
    if (lane < 32) {
        ((float4*)s)[(long long)n * 32 + lane] = f4add(t, u);
    }
}

// ---------------------------------------------------------------------------
// Kernel 3: per-node MLP. Block = 256 threads, 16 nodes/block.
// ---------------------------------------------------------------------------
__global__ __launch_bounds__(256) void node_kernel(
        const float* __restrict__ s,
        const float* __restrict__ node_sca,
        const float* __restrict__ W1, const float* __restrict__ b1,
        const float* __restrict__ W2, const float* __restrict__ b2,
        float* __restrict__ out0,
        int N) {
    __shared__ float s_lds[16][128];
    __shared__ float h_lds[16][128];

    const int tid = threadIdx.x;
    const int nbase = blockIdx.x * 16;

    {
        const float4* sg = (const float4*)s;
        #pragma unroll
        for (int step = 0; step < 2; ++step) {
            int idx = tid + step * 256;
            int m = idx >> 5;
            int q = idx & 31;
            int n = nbase + m;
            float4 v = make_float4(0.f, 0.f, 0.f, 0.f);
            if (n < N) v = sg[(long long)n * 32 + q];
            *(float4*)&s_lds[m][q * 4] = v;
        }
    }
    __syncthreads();

    const int j = tid & 127;
    const int mbase = (tid >> 7) * 8;

    {
        float acc[8] = {0.f, 0.f, 0.f, 0.f, 0.f, 0.f, 0.f, 0.f};
        #pragma unroll 4
        for (int f0 = 0; f0 < 128; f0 += 4) {
            const float w0 = W1[(f0 + 0) * 128 + j];
            const float w1 = W1[(f0 + 1) * 128 + j];
            const float w2 = W1[(f0 + 2) * 128 + j];
            const float w3 = W1[(f0 + 3) * 128 + j];
            #pragma unroll
            for (int m = 0; m < 8; ++m) {
                float4 sv = *(const float4*)&s_lds[mbase + m][f0];
                acc[m] = fmaf(sv.x, w0, acc[m]);
                acc[m] = fmaf(sv.y, w1, acc[m]);
                acc[m] = fmaf(sv.z, w2, acc[m]);
                acc[m] = fmaf(sv.w, w3, acc[m]);
            }
        }
        const float bj = b1[j];
        #pragma unroll
        for (int m = 0; m < 8; ++m) {
            float x = acc[m] + bj;
            float h = fmaxf(x, 0.f) + log1pf(expf(-fabsf(x))) - LOG2F;
            h_lds[mbase + m][j] = h;
        }
    }
    __syncthreads();

    {
        float acc[8] = {0.f, 0.f, 0.f, 0.f, 0.f, 0.f, 0.f, 0.f};
        #pragma unroll 4
        for (int f0 = 0; f0 < 128; f0 += 4) {
            const float w0 = W2[(f0 + 0) * 128 + j];
            const float w1 = W2[(f0 + 1) * 128 + j];
            const float w2 = W2[(f0 + 2) * 128 + j];
            const float w3 = W2[(f0 + 3) * 128 + j];
            #pragma unroll
            for (int m = 0; m < 8; ++m) {
                float4 hv = *(const float4*)&h_lds[mbase + m][f0];
                acc[m] = fmaf(hv.x, w0, acc[m]);
                acc[m] = fmaf(hv.y, w1, acc[m]);
                acc[m] = fmaf(hv.z, w2, acc[m]);
                acc[m] = fmaf(hv.w, w3, acc[m]);
            }
        }
        const float bj = b2[j];
        #pragma unroll
        for (int m = 0; m < 8; ++m) {
            const int n = nbase + mbase + m;
            if (n < N) {
                float v = node_sca[(long long)n * 128 + j] + acc[m] + bj;
                __builtin_nontemporal_store(v, &out0[(long long)n * 128 + j]);
            }
        }
    }
}

extern "C" void kernel_launch(void* const* d_in, const int* in_sizes, int n_in,
                              void* d_out, int out_size, void* d_ws, size_t ws_size,
                              hipStream_t stream) {
    const float* node_sca   = (const float*)d_in[0];
    const float* node_vec   = (const float*)d_in[1];
    const float* edge_feats = (const float*)d_in[2];
    const void*  edge_index = d_in[3];
    const float* W1 = (const float*)d_in[4];
    const float* b1 = (const float*)d_in[5];
    const float* W2 = (const float*)d_in[6];
    const float* b2 = (const float*)d_in[7];

    const int H = in_sizes[5];            // 128
    const int N = in_sizes[0] / H;        // 25000
    const int E = in_sizes[3] / 2;        // 400000

    char* w = (char*)d_ws;
    auto take = [&](size_t bytes) {
        char* p = w;
        w += (bytes + 15) & ~(size_t)15;
        return p;
    };
    int*   counts  = (int*)take(sizeof(int) * (size_t)N);
    int*   elist64 = (int*)take(sizeof(int) * (size_t)N * CAP);
    int*   ovf_cnt = (int*)take(sizeof(int));
    int*   ovf_n   = (int*)take(sizeof(int) * (size_t)E);
    int*   ovf_e   = (int*)take(sizeof(int) * (size_t)E);
    float* s       = (float*)take(sizeof(float) * (size_t)N * 128);
    int*   flag    = (int*)take(sizeof(int));

    float* out0 = (float*)d_out;               // (N, 128)
    float* out1 = out0 + (long long)N * 128;   // (N, 3, 128)

    zero_detect_kernel<<<(N + 255) / 256, 256, 0, stream>>>(
        (const unsigned int*)edge_index, counts, ovf_cnt, flag, N);

    bucket_kernel<<<(E + 255) / 256, 256, 0, stream>>>(
        edge_index, flag, counts, elist64, ovf_cnt, ovf_n, ovf_e, E);

    gather_kernel<<<(N + 3) / 4, 256, 0, stream>>>(
        (const float4*)edge_feats, elist64, counts, ovf_cnt, ovf_n, ovf_e,
        node_vec, out1, s, N);

    node_kernel<<<(N + 15) / 16, 256, 0, stream>>>(
        s, node_sca, W1, b1, W2, b2, out0, N);
}